// Round 1
// baseline (5298.202 us; speedup 1.0000x reference)
//
#include <hip/hip_runtime.h>
#include <math.h>

// Problem constants
#define VOCAB 32000
#define BATCH 64
#define FRAME 4096
#define HID   256
#define VSTEP 80
#define CSTEP 50
#define TSEQ  129   // VSTEP + CSTEP - 1
#define DEC_T 49    // CSTEP - 1

__device__ __forceinline__ float sigm(float x) { return 1.0f / (1.0f + expf(-x)); }

// ---------------------------------------------------------------------------
// Generic fp32 GEMM-NT:  C[m][n] = sum_k A[m*lda+k] * W[n*ldb+k]  (+bias)
// tile 64x64, 256 threads, 4x4 microtile, K staged in LDS chunks of 16.
// grid = (Mtiles, Ntiles, KS). z-slice handles K columns [z*K, (z+1)*K).
// Output row remap: orow = (m/inT)*outT + (m%inT)   (identity when inT==outT==1)
// ---------------------------------------------------------------------------
__global__ __launch_bounds__(256)
void gemm_nt(const float* __restrict__ A, int lda,
             const float* __restrict__ W, int ldb,
             float* __restrict__ C, long long cz_stride, int ldc,
             int K,
             const float* __restrict__ bias0, const float* __restrict__ bias1,
             int inT, int outT)
{
    const int mt = blockIdx.x, nt = blockIdx.y, z = blockIdx.z;
    const int tid = threadIdx.x;
    A += (size_t)mt * 64 * lda + (size_t)z * K;
    W += (size_t)nt * 64 * ldb + (size_t)z * K;
    C += (size_t)z * cz_stride;

    __shared__ float As[16][68];
    __shared__ float Bs[16][68];

    const int tx = tid & 15, ty = tid >> 4;
    const int lr = tid >> 2;          // 0..63 staging row
    const int lk = (tid & 3) * 4;     // 0,4,8,12 staging k-offset

    float acc[4][4] = {};

    for (int k0 = 0; k0 < K; k0 += 16) {
        float4 a4 = *(const float4*)(A + (size_t)lr * lda + k0 + lk);
        float4 b4 = *(const float4*)(W + (size_t)lr * ldb + k0 + lk);
        As[lk + 0][lr] = a4.x; As[lk + 1][lr] = a4.y;
        As[lk + 2][lr] = a4.z; As[lk + 3][lr] = a4.w;
        Bs[lk + 0][lr] = b4.x; Bs[lk + 1][lr] = b4.y;
        Bs[lk + 2][lr] = b4.z; Bs[lk + 3][lr] = b4.w;
        __syncthreads();
#pragma unroll
        for (int k = 0; k < 16; ++k) {
            float4 av = *(const float4*)&As[k][ty * 4];
            float4 bv = *(const float4*)&Bs[k][tx * 4];
            acc[0][0] += av.x * bv.x; acc[0][1] += av.x * bv.y;
            acc[0][2] += av.x * bv.z; acc[0][3] += av.x * bv.w;
            acc[1][0] += av.y * bv.x; acc[1][1] += av.y * bv.y;
            acc[1][2] += av.y * bv.z; acc[1][3] += av.y * bv.w;
            acc[2][0] += av.z * bv.x; acc[2][1] += av.z * bv.y;
            acc[2][2] += av.z * bv.z; acc[2][3] += av.z * bv.w;
            acc[3][0] += av.w * bv.x; acc[3][1] += av.w * bv.y;
            acc[3][2] += av.w * bv.z; acc[3][3] += av.w * bv.w;
        }
        __syncthreads();
    }

    const int colbase = nt * 64 + tx * 4;
    float badd[4] = {0.f, 0.f, 0.f, 0.f};
    if (bias0) {
#pragma unroll
        for (int j = 0; j < 4; ++j) badd[j] += bias0[colbase + j];
    }
    if (bias1) {
#pragma unroll
        for (int j = 0; j < 4; ++j) badd[j] += bias1[colbase + j];
    }
#pragma unroll
    for (int i = 0; i < 4; ++i) {
        int m = mt * 64 + ty * 4 + i;
        int orow = (m / inT) * outT + (m % inT);
        float4 o;
        o.x = acc[i][0] + badd[0]; o.y = acc[i][1] + badd[1];
        o.z = acc[i][2] + badd[2]; o.w = acc[i][3] + badd[3];
        *(float4*)(C + (size_t)orow * ldc + colbase) = o;
    }
}

// Sum 4 split-K partials of GEMM1 and add b1.
__global__ void reduce_v(const float* __restrict__ vpart, const float* __restrict__ b1,
                         float* __restrict__ v)
{
    int g = blockIdx.x * 256 + threadIdx.x;      // 327680 float4s
    int m = g >> 6, nf = (g & 63) * 4;
    size_t off = (size_t)m * 256 + nf;
    const size_t zs = (size_t)5120 * 256;
    float4 a = *(const float4*)(vpart + off);
    float4 b = *(const float4*)(vpart + zs + off);
    float4 c = *(const float4*)(vpart + 2 * zs + off);
    float4 d = *(const float4*)(vpart + 3 * zs + off);
    float4 r;
    r.x = a.x + b.x + c.x + d.x + b1[nf + 0];
    r.y = a.y + b.y + c.y + d.y + b1[nf + 1];
    r.z = a.z + b.z + c.z + d.z + b1[nf + 2];
    r.w = a.w + b.w + c.w + d.w + b1[nf + 3];
    *(float4*)(v + off) = r;
}

// XG rows for t in [80,129): input x is zero, gates_x = bih + bhh.
__global__ void fill_bias(float* __restrict__ XG, const float* __restrict__ bih,
                          const float* __restrict__ bhh)
{
    int blk = blockIdx.x;                 // 64*49 blocks
    int b = blk / DEC_T, t = VSTEP + blk % DEC_T;
    float* row = XG + ((size_t)b * TSEQ + t) * 1024;
    int j = threadIdx.x * 4;
    float4 o;
    o.x = bih[j + 0] + bhh[j + 0]; o.y = bih[j + 1] + bhh[j + 1];
    o.z = bih[j + 2] + bhh[j + 2]; o.w = bih[j + 3] + bhh[j + 3];
    *(float4*)(row + j) = o;
}

// Wcat[j][0:256] = l2_wih[j][0:256] (emb part); Wcat[j][256:512] = l2_whh[j][:]
__global__ void pack_wcat(const float* __restrict__ wih, const float* __restrict__ whh,
                          float* __restrict__ Wcat)
{
    int g = blockIdx.x * 256 + threadIdx.x;   // 131072 float4s
    int j = g >> 7, p = g & 127;
    float4 v;
    if (p < 64) v = *(const float4*)(wih + (size_t)j * 512 + p * 4);
    else        v = *(const float4*)(whh + (size_t)j * 256 + (p - 64) * 4);
    *(float4*)(Wcat + (size_t)j * 512 + p * 4) = v;
}

// Zero the per-batch step counters (both layers' regions).
__global__ void zero_flags(unsigned* __restrict__ f)
{
    f[blockIdx.x * 256 + threadIdx.x] = 0u;
}

// ---------------------------------------------------------------------------
// Multi-CU LSTM recurrence with register-resident weights.
// 8 blocks per batch element; block (b,p) owns cell dims [p*32, p*32+32), i.e.
// gate rows {g*256 + p*32 + d}. Each thread holds 64 Whh floats in VGPRs
// (zero weight re-streaming). Per step the 8 blocks exchange their 32 h-values
// through an agent-scope double-buffered global buffer, gated by a per-batch
// release/acquire counter (8 increments per step, monotone).
//
// Safety: grid = 512 blocks, <=128 VGPR (launch_bounds), ~1.6 KB LDS
// -> 2 blocks/CU -> whole grid co-resident; group mapping b = bid>>3 keeps any
// in-order prefix composed of complete groups. Double-buffer parity + the
// counter provably prevent a fast block from overwriting unread h-values.
// ---------------------------------------------------------------------------
__global__ __launch_bounds__(512, 4)
void lstm_sync(const float* __restrict__ Whh,   // [1024][256] row-major
               const float* __restrict__ XG,    // [64][TSEQ][1024]
               int nsteps,
               float* __restrict__ h_seq,       // [64][TSEQ][256] or null
               float* __restrict__ h_fin,
               float* __restrict__ c_fin,
               float* __restrict__ hx,          // [2][64][256] exchange
               unsigned* __restrict__ flags)    // [64*32] padded counters
{
    const int bid = blockIdx.x;
    const int b = bid >> 3, p = bid & 7;
    const int tid = threadIdx.x;
    const int r = tid >> 2, q = tid & 3;        // r in [0,128), q in [0,4)
    const int gate = r >> 5;                    // 0..3 (i,f,g,o)
    const int D = p * 32 + (r & 31);            // global cell dim
    const int j = gate * 256 + D;               // gate row in [0,1024)

    // h partitioned across q-slices, stride 68 so the four simultaneous b128
    // reads (q=0..3, same kk) land on disjoint bank groups.
    __shared__ float hs4[4 * 68];
    __shared__ float gbuf[128];

    // 64 weight floats per thread -> 16 float4 VGPR tuples (static indexing).
    float4 wv[16];
    {
        const float* wrow = Whh + (size_t)j * 256 + q * 64;
#pragma unroll
        for (int kk = 0; kk < 16; ++kk)
            wv[kk] = *(const float4*)(wrow + kk * 4);
    }

    if (tid < 272) hs4[tid] = 0.f;
    float creg = 0.f, hreg = 0.f;
    const float* xgb = XG + (size_t)b * TSEQ * 1024;
    float xgv = (q == 0) ? xgb[j] : 0.f;        // preloaded XG row for t=0
    unsigned* flag = flags + b * 32;            // 128B-padded counter
    const int q68 = q * 68;
    __syncthreads();

    for (int t = 0; t < nsteps; ++t) {
        // acc = Whh[j][q*64 : q*64+64] . h[q*64 : q*64+64]
        float acc = 0.f;
#pragma unroll
        for (int kk = 0; kk < 16; ++kk) {
            float4 h4 = *(const float4*)&hs4[q68 + kk * 4];
            acc += wv[kk].x * h4.x + wv[kk].y * h4.y
                 + wv[kk].z * h4.z + wv[kk].w * h4.w;
        }
        acc += __shfl_xor(acc, 1);
        acc += __shfl_xor(acc, 2);
        if (q == 0) gbuf[r] = acc + xgv;
        // prefetch next step's XG row while the group synchronizes
        if (q == 0 && t + 1 < nsteps) xgv = xgb[(size_t)(t + 1) * 1024 + j];
        __syncthreads();

        if (tid < 32) {
            float ig = gbuf[tid], fg = gbuf[32 + tid];
            float gg = gbuf[64 + tid], og = gbuf[96 + tid];
            float cn = sigm(fg) * creg + sigm(ig) * tanhf(gg);
            float hn = sigm(og) * tanhf(cn);
            creg = cn; hreg = hn;
            __hip_atomic_store(&hx[((size_t)(t & 1) * 64 + b) * 256 + p * 32 + tid],
                               hn, __ATOMIC_RELAXED, __HIP_MEMORY_SCOPE_AGENT);
            if (h_seq) h_seq[((size_t)b * TSEQ + t) * 256 + p * 32 + tid] = hn;
        }
        __syncthreads();   // barrier drains vmcnt -> hx stores are visible
        if (tid == 0) {
            __hip_atomic_fetch_add(flag, 1u, __ATOMIC_RELEASE,
                                   __HIP_MEMORY_SCOPE_AGENT);
            const unsigned target = 8u * (unsigned)(t + 1);
            while (__hip_atomic_load(flag, __ATOMIC_ACQUIRE,
                                     __HIP_MEMORY_SCOPE_AGENT) < target) {}
        }
        __syncthreads();
        if (tid < 256) {
            float v = __hip_atomic_load(&hx[((size_t)(t & 1) * 64 + b) * 256 + tid],
                                        __ATOMIC_RELAXED, __HIP_MEMORY_SCOPE_AGENT);
            hs4[(tid >> 6) * 68 + (tid & 63)] = v;
        }
        __syncthreads();
    }

    if (h_fin && tid < 32) {
        h_fin[b * 256 + p * 32 + tid] = hreg;
        c_fin[b * 256 + p * 32 + tid] = creg;
    }
}

// Decode cell: sum 4 split-K gate partials + precomputed ctx-gates row, LSTM cell.
__global__ void dec_cell(const float* __restrict__ gpart, const float* __restrict__ allg,
                         float* __restrict__ h, float* __restrict__ c)
{
    const int b = blockIdx.x, d = threadIdx.x;
    const size_t zs = (size_t)64 * 1024;
    float g4[4];
#pragma unroll
    for (int gg = 0; gg < 4; ++gg) {
        int j = gg * 256 + d;
        float s = allg[(size_t)b * TSEQ * 1024 + j];
        s += gpart[(size_t)b * 1024 + j];
        s += gpart[zs + (size_t)b * 1024 + j];
        s += gpart[2 * zs + (size_t)b * 1024 + j];
        s += gpart[3 * zs + (size_t)b * 1024 + j];
        g4[gg] = s;
    }
    float cn = sigm(g4[1]) * c[b * 256 + d] + sigm(g4[0]) * tanhf(g4[2]);
    float hn = sigm(g4[3]) * tanhf(cn);
    c[b * 256 + d] = cn;
    h[b * 256 + d] = hn;
}

// Logits tile: all 64 batch rows x 64 vocab cols, K=256. Writes cap_prob and
// per-(batch, vocab-slice) argmax partials. First-max tie rule preserved by
// ascending-index scans with strict >.
__global__ __launch_bounds__(256)
void dec_logits(const float* __restrict__ h, const float* __restrict__ w2,
                const float* __restrict__ b2, float* __restrict__ outp,
                float* __restrict__ pmax)
{
    const int nt = blockIdx.x;   // 500 slices of 64 vocab cols
    const int tid = threadIdx.x, tx = tid & 15, ty = tid >> 4;
    __shared__ float As[16][68];
    __shared__ float Bs[16][68];
    __shared__ float pmv[64][17];
    __shared__ float pmi[64][17];

    const float* W = w2 + (size_t)nt * 64 * 256;
    const int lr = tid >> 2, lk = (tid & 3) * 4;
    float acc[4][4] = {};

    for (int k0 = 0; k0 < 256; k0 += 16) {
        float4 a4 = *(const float4*)(h + (size_t)lr * 256 + k0 + lk);
        float4 b4 = *(const float4*)(W + (size_t)lr * 256 + k0 + lk);
        As[lk + 0][lr] = a4.x; As[lk + 1][lr] = a4.y;
        As[lk + 2][lr] = a4.z; As[lk + 3][lr] = a4.w;
        Bs[lk + 0][lr] = b4.x; Bs[lk + 1][lr] = b4.y;
        Bs[lk + 2][lr] = b4.z; Bs[lk + 3][lr] = b4.w;
        __syncthreads();
#pragma unroll
        for (int k = 0; k < 16; ++k) {
            float4 av = *(const float4*)&As[k][ty * 4];
            float4 bv = *(const float4*)&Bs[k][tx * 4];
            acc[0][0] += av.x * bv.x; acc[0][1] += av.x * bv.y;
            acc[0][2] += av.x * bv.z; acc[0][3] += av.x * bv.w;
            acc[1][0] += av.y * bv.x; acc[1][1] += av.y * bv.y;
            acc[1][2] += av.y * bv.z; acc[1][3] += av.y * bv.w;
            acc[2][0] += av.z * bv.x; acc[2][1] += av.z * bv.y;
            acc[2][2] += av.z * bv.z; acc[2][3] += av.z * bv.w;
            acc[3][0] += av.w * bv.x; acc[3][1] += av.w * bv.y;
            acc[3][2] += av.w * bv.z; acc[3][3] += av.w * bv.w;
        }
        __syncthreads();
    }

    const int colbase = nt * 64 + tx * 4;
    float bb[4];
#pragma unroll
    for (int j = 0; j < 4; ++j) bb[j] = b2[colbase + j];

#pragma unroll
    for (int i = 0; i < 4; ++i) {
        int b = ty * 4 + i;
        float4 v;
        v.x = acc[i][0] + bb[0]; v.y = acc[i][1] + bb[1];
        v.z = acc[i][2] + bb[2]; v.w = acc[i][3] + bb[3];
        *(float4*)(outp + (size_t)b * ((size_t)DEC_T * VOCAB) + colbase) = v;
        float bestv = v.x; int bestj = colbase;
        if (v.y > bestv) { bestv = v.y; bestj = colbase + 1; }
        if (v.z > bestv) { bestv = v.z; bestj = colbase + 2; }
        if (v.w > bestv) { bestv = v.w; bestj = colbase + 3; }
        pmv[b][tx] = bestv;
        pmi[b][tx] = (float)bestj;
    }
    __syncthreads();
    if (tid < 64) {
        float bv = pmv[tid][0], bj = pmi[tid][0];
#pragma unroll
        for (int s = 1; s < 16; ++s) {
            if (pmv[tid][s] > bv) { bv = pmv[tid][s]; bj = pmi[tid][s]; }
        }
        pmax[((size_t)tid * 500 + nt) * 2 + 0] = bv;
        pmax[((size_t)tid * 500 + nt) * 2 + 1] = bj;
    }
}

// Reduce 500 argmax partials per batch row -> token; emit caption (as float)
// and next-step concat input y = [emb[tok], h].
__global__ void dec_finish(const float* __restrict__ pmax, const float* __restrict__ emb,
                           const float* __restrict__ h, float* __restrict__ y,
                           float* __restrict__ cap_out)
{
    const int b = blockIdx.x, tid = threadIdx.x;
    __shared__ float bv[256];
    __shared__ int   bi[256];
    float best = -INFINITY; int bidx = 0x7fffffff;
    for (int s = tid; s < 500; s += 256) {
        float v = pmax[((size_t)b * 500 + s) * 2 + 0];
        int   ix = (int)pmax[((size_t)b * 500 + s) * 2 + 1];
        if (v > best || (v == best && ix < bidx)) { best = v; bidx = ix; }
    }
    bv[tid] = best; bi[tid] = bidx;
    __syncthreads();
    for (int s = 128; s > 0; s >>= 1) {
        if (tid < s) {
            if (bv[tid + s] > bv[tid] ||
                (bv[tid + s] == bv[tid] && bi[tid + s] < bi[tid])) {
                bv[tid] = bv[tid + s]; bi[tid] = bi[tid + s];
            }
        }
        __syncthreads();
    }
    int tok = bi[0];
    if (tid == 0) cap_out[(size_t)b * DEC_T] = (float)tok;
    y[(size_t)b * 512 + tid]       = emb[(size_t)tok * 256 + tid];
    y[(size_t)b * 512 + 256 + tid] = h[(size_t)b * 256 + tid];
}

// y for t=0: tok = BOS = 0.
__global__ void y_init(const float* __restrict__ emb, const float* __restrict__ h,
                       float* __restrict__ y)
{
    const int b = blockIdx.x, tid = threadIdx.x;
    y[(size_t)b * 512 + tid]       = emb[tid];
    y[(size_t)b * 512 + 256 + tid] = h[(size_t)b * 256 + tid];
}

// ---------------------------------------------------------------------------
extern "C" void kernel_launch(void* const* d_in, const int* in_sizes, int n_in,
                              void* d_out, int out_size, void* d_ws, size_t ws_size,
                              hipStream_t stream)
{
    const float* video  = (const float*)d_in[0];
    const float* w1     = (const float*)d_in[1];
    const float* b1     = (const float*)d_in[2];
    const float* w2     = (const float*)d_in[3];
    const float* b2     = (const float*)d_in[4];
    const float* l1_wih = (const float*)d_in[5];
    const float* l1_whh = (const float*)d_in[6];
    const float* l1_bih = (const float*)d_in[7];
    const float* l1_bhh = (const float*)d_in[8];
    const float* l2_wih = (const float*)d_in[9];
    const float* l2_whh = (const float*)d_in[10];
    const float* l2_bih = (const float*)d_in[11];
    const float* l2_bhh = (const float*)d_in[12];
    const float* emb    = (const float*)d_in[13];

    float* out_f = (float*)d_out;           // [64*49] caption (as float) | [64*49*32000] cap_prob
    float* ws    = (float*)d_ws;

    // workspace layout (floats)
    float* v      = ws;                            // 5120*256      = 1,310,720
    float* vid    = v      + 1310720;              // 64*129*256    = 2,113,536
    float* hx     = vid    + 2113536;              // 2*64*256 = 32,768 (old wp1 region)
    unsigned* flags = (unsigned*)(hx + 262144);    // 4096 uints (old wp2 region)
    float* wcat   = hx     + 524288;               // 1024*512      = 524,288
    float* hbuf   = wcat   + 524288;               // 16,384
    float* cbuf   = hbuf   + 16384;                // 16,384
    float* ybuf   = cbuf   + 16384;                // 64*512        = 32,768
    float* gpart  = ybuf   + 32768;                // 4*64*1024     = 262,144
    float* pmax   = gpart  + 262144;               // 64*500*2      = 64,000
    float* xg     = pmax   + 64000;                // 64*129*1024   = 8,454,144  (also holds gemm1 partials)
    float* vpart  = xg;                            // 4*5120*256 = 5,242,880 <= XG region

    // prep: flags + concat weights
    zero_flags<<<16, 256, 0, stream>>>(flags);
    pack_wcat<<<512, 256, 0, stream>>>(l2_wih, l2_whh, wcat);

    // GEMM1: v = video @ w1.T + b1   (split-K=4 for load balance, then reduce)
    gemm_nt<<<dim3(80, 4, 4), 256, 0, stream>>>(video, FRAME, w1, FRAME,
                                                vpart, (long long)5120 * 256, 256,
                                                1024, nullptr, nullptr, 1, 1);
    reduce_v<<<1280, 256, 0, stream>>>(vpart, b1, v);

    // XG = v @ l1_wih.T + (bih + bhh), rows remapped b*129+t; bias-only rows t>=80
    gemm_nt<<<dim3(80, 16, 1), 256, 0, stream>>>(v, HID, l1_wih, HID,
                                                 xg, 0, 1024, HID,
                                                 l1_bih, l1_bhh, VSTEP, TSEQ);
    fill_bias<<<64 * DEC_T, 256, 0, stream>>>(xg, l1_bih, l1_bhh);

    // LSTM1: 129 steps, emits vid_out (8 blocks per batch, weights in VGPRs)
    lstm_sync<<<512, 512, 0, stream>>>(l1_whh, xg, TSEQ, vid, nullptr, nullptr,
                                       hx, flags);

    // XG = vid_out @ l2_wih[:,256:].T + (bih + bhh)   (x first half is zeros for enc)
    gemm_nt<<<dim3(129, 16, 1), 256, 0, stream>>>(vid, HID, l2_wih + 256, 512,
                                                  xg, 0, 1024, HID,
                                                  l2_bih, l2_bhh, 1, 1);

    // LSTM2 encode: 80 steps -> (h2, c2)
    lstm_sync<<<512, 512, 0, stream>>>(l2_whh, xg, VSTEP, nullptr, hbuf, cbuf,
                                       hx, flags + 64 * 32);

    // decode
    y_init<<<64, 256, 0, stream>>>(emb, hbuf, ybuf);
    for (int t = 0; t < DEC_T; ++t) {
        // gates partials = y @ Wcat.T  (K=512 split 4 ways)
        gemm_nt<<<dim3(1, 16, 4), 256, 0, stream>>>(ybuf, 512, wcat, 512,
                                                    gpart, (long long)64 * 1024, 1024,
                                                    128, nullptr, nullptr, 1, 1);
        dec_cell<<<64, 256, 0, stream>>>(gpart, xg + (size_t)(VSTEP + t) * 1024, hbuf, cbuf);
        dec_logits<<<500, 256, 0, stream>>>(hbuf, w2, b2,
                                            out_f + 3136 + (size_t)t * VOCAB, pmax);
        dec_finish<<<64, 256, 0, stream>>>(pmax, emb, hbuf, ybuf, out_f + t);
    }
}

// Round 2
// 3053.687 us; speedup vs baseline: 1.7350x; 1.7350x over previous
//
#include <hip/hip_runtime.h>
#include <math.h>

// Problem constants
#define VOCAB 32000
#define BATCH 64
#define FRAME 4096
#define HID   256
#define VSTEP 80
#define CSTEP 50
#define TSEQ  129   // VSTEP + CSTEP - 1
#define DEC_T 49    // CSTEP - 1

__device__ __forceinline__ float sigm(float x) { return 1.0f / (1.0f + expf(-x)); }

// ---------------------------------------------------------------------------
// Generic fp32 GEMM-NT:  C[m][n] = sum_k A[m*lda+k] * W[n*ldb+k]  (+bias)
// tile 64x64, 256 threads, 4x4 microtile, K staged in LDS chunks of 16.
// grid = (Mtiles, Ntiles, KS). z-slice handles K columns [z*K, (z+1)*K).
// Output row remap: orow = (m/inT)*outT + (m%inT)   (identity when inT==outT==1)
// ---------------------------------------------------------------------------
__global__ __launch_bounds__(256)
void gemm_nt(const float* __restrict__ A, int lda,
             const float* __restrict__ W, int ldb,
             float* __restrict__ C, long long cz_stride, int ldc,
             int K,
             const float* __restrict__ bias0, const float* __restrict__ bias1,
             int inT, int outT)
{
    const int mt = blockIdx.x, nt = blockIdx.y, z = blockIdx.z;
    const int tid = threadIdx.x;
    A += (size_t)mt * 64 * lda + (size_t)z * K;
    W += (size_t)nt * 64 * ldb + (size_t)z * K;
    C += (size_t)z * cz_stride;

    __shared__ float As[16][68];
    __shared__ float Bs[16][68];

    const int tx = tid & 15, ty = tid >> 4;
    const int lr = tid >> 2;          // 0..63 staging row
    const int lk = (tid & 3) * 4;     // 0,4,8,12 staging k-offset

    float acc[4][4] = {};

    for (int k0 = 0; k0 < K; k0 += 16) {
        float4 a4 = *(const float4*)(A + (size_t)lr * lda + k0 + lk);
        float4 b4 = *(const float4*)(W + (size_t)lr * ldb + k0 + lk);
        As[lk + 0][lr] = a4.x; As[lk + 1][lr] = a4.y;
        As[lk + 2][lr] = a4.z; As[lk + 3][lr] = a4.w;
        Bs[lk + 0][lr] = b4.x; Bs[lk + 1][lr] = b4.y;
        Bs[lk + 2][lr] = b4.z; Bs[lk + 3][lr] = b4.w;
        __syncthreads();
#pragma unroll
        for (int k = 0; k < 16; ++k) {
            float4 av = *(const float4*)&As[k][ty * 4];
            float4 bv = *(const float4*)&Bs[k][tx * 4];
            acc[0][0] += av.x * bv.x; acc[0][1] += av.x * bv.y;
            acc[0][2] += av.x * bv.z; acc[0][3] += av.x * bv.w;
            acc[1][0] += av.y * bv.x; acc[1][1] += av.y * bv.y;
            acc[1][2] += av.y * bv.z; acc[1][3] += av.y * bv.w;
            acc[2][0] += av.z * bv.x; acc[2][1] += av.z * bv.y;
            acc[2][2] += av.z * bv.z; acc[2][3] += av.z * bv.w;
            acc[3][0] += av.w * bv.x; acc[3][1] += av.w * bv.y;
            acc[3][2] += av.w * bv.z; acc[3][3] += av.w * bv.w;
        }
        __syncthreads();
    }

    const int colbase = nt * 64 + tx * 4;
    float badd[4] = {0.f, 0.f, 0.f, 0.f};
    if (bias0) {
#pragma unroll
        for (int j = 0; j < 4; ++j) badd[j] += bias0[colbase + j];
    }
    if (bias1) {
#pragma unroll
        for (int j = 0; j < 4; ++j) badd[j] += bias1[colbase + j];
    }
#pragma unroll
    for (int i = 0; i < 4; ++i) {
        int m = mt * 64 + ty * 4 + i;
        int orow = (m / inT) * outT + (m % inT);
        float4 o;
        o.x = acc[i][0] + badd[0]; o.y = acc[i][1] + badd[1];
        o.z = acc[i][2] + badd[2]; o.w = acc[i][3] + badd[3];
        *(float4*)(C + (size_t)orow * ldc + colbase) = o;
    }
}

// Sum 4 split-K partials of GEMM1 and add b1.
__global__ void reduce_v(const float* __restrict__ vpart, const float* __restrict__ b1,
                         float* __restrict__ v)
{
    int g = blockIdx.x * 256 + threadIdx.x;      // 327680 float4s
    int m = g >> 6, nf = (g & 63) * 4;
    size_t off = (size_t)m * 256 + nf;
    const size_t zs = (size_t)5120 * 256;
    float4 a = *(const float4*)(vpart + off);
    float4 b = *(const float4*)(vpart + zs + off);
    float4 c = *(const float4*)(vpart + 2 * zs + off);
    float4 d = *(const float4*)(vpart + 3 * zs + off);
    float4 r;
    r.x = a.x + b.x + c.x + d.x + b1[nf + 0];
    r.y = a.y + b.y + c.y + d.y + b1[nf + 1];
    r.z = a.z + b.z + c.z + d.z + b1[nf + 2];
    r.w = a.w + b.w + c.w + d.w + b1[nf + 3];
    *(float4*)(v + off) = r;
}

// XG rows for t in [80,129): input x is zero, gates_x = bih + bhh.
__global__ void fill_bias(float* __restrict__ XG, const float* __restrict__ bih,
                          const float* __restrict__ bhh)
{
    int blk = blockIdx.x;                 // 64*49 blocks
    int b = blk / DEC_T, t = VSTEP + blk % DEC_T;
    float* row = XG + ((size_t)b * TSEQ + t) * 1024;
    int j = threadIdx.x * 4;
    float4 o;
    o.x = bih[j + 0] + bhh[j + 0]; o.y = bih[j + 1] + bhh[j + 1];
    o.z = bih[j + 2] + bhh[j + 2]; o.w = bih[j + 3] + bhh[j + 3];
    *(float4*)(row + j) = o;
}

// Wcat[j][0:256] = l2_wih[j][0:256] (emb part); Wcat[j][256:512] = l2_whh[j][:]
__global__ void pack_wcat(const float* __restrict__ wih, const float* __restrict__ whh,
                          float* __restrict__ Wcat)
{
    int g = blockIdx.x * 256 + threadIdx.x;   // 131072 float4s
    int j = g >> 7, p = g & 127;
    float4 v;
    if (p < 64) v = *(const float4*)(wih + (size_t)j * 512 + p * 4);
    else        v = *(const float4*)(whh + (size_t)j * 256 + (p - 64) * 4);
    *(float4*)(Wcat + (size_t)j * 512 + p * 4) = v;
}

// Zero the per-batch step flag slots (both layers' regions).
__global__ void zero_flags(unsigned* __restrict__ f)
{
    f[blockIdx.x * 256 + threadIdx.x] = 0u;
}

// ---------------------------------------------------------------------------
// Multi-CU LSTM recurrence, register-resident weights, L2-safe sync.
//
// 4 blocks per batch element; block (b,p) owns cell dims [p*64, p*64+64), i.e.
// 256 gate rows (4 gates x 64 dims) = 256 KB of Whh = 32 float4 VGPRs/thread.
// __launch_bounds__(512,2) caps VGPR at 256 so the weight array stays resident
// (round-1 failure: cap 128 forced the compiler to re-load weights per step;
// VGPR_Count=52 proved it).
//
// Cross-block sync per step uses ONLY relaxed agent-scope atomics (per-access
// sc1, no buffer_inv/wbl2 cache maintenance — round-1's acquire/release spin
// invalidated the XCD L2s every poll iteration, 13.5 us/step). Producer order:
// h-stores then s_waitcnt vmcnt(0) then per-block slot-flag store (same wave,
// so vmcnt covers the data stores). Consumer: poll 4 slots (monotone counters)
// then read; double-buffered hx by step parity — a block can only reach parity
// reuse after observing flags that prove all peers consumed the old buffer.
//
// Deadlock safety: 256 blocks, <=256 VGPR, 2 KB LDS -> every block resident
// (>=1 per CU on 256 CUs); group mapping b = bid>>2 keeps any in-order
// dispatch prefix composed of complete groups.
// ---------------------------------------------------------------------------
__global__ __launch_bounds__(512, 2)
void lstm_sync(const float* __restrict__ Whh,   // [1024][256] row-major
               const float* __restrict__ XG,    // [64][TSEQ][1024]
               int nsteps,
               float* __restrict__ h_seq,       // [64][TSEQ][256] or null
               float* __restrict__ h_fin,
               float* __restrict__ c_fin,
               float* __restrict__ hx,          // [2][64][256] exchange
               unsigned* __restrict__ flags)    // [64][32] padded slot flags
{
    const int bid = blockIdx.x;
    const int b = bid >> 2, p = bid & 3;
    const int tid = threadIdx.x;
    const int r = tid >> 1, q = tid & 1;        // r: local gate row 0..255
    const int g = r >> 6, d = r & 63;           // gate, local dim
    const int j = g * 256 + p * 64 + d;         // global gate row

    __shared__ float hs[256];
    __shared__ float gbuf[256];

    // 128 weight floats per thread -> 32 float4 VGPR tuples (static indexing).
    float4 wv[32];
    {
        const float* wrow = Whh + (size_t)j * 256 + q * 128;
#pragma unroll
        for (int kk = 0; kk < 32; ++kk)
            wv[kk] = *(const float4*)(wrow + kk * 4);
    }

    if (tid < 256) hs[tid] = 0.f;
    float creg = 0.f, hreg = 0.f;
    const float* xgb = XG + (size_t)b * TSEQ * 1024;
    float xgv = (q == 0) ? xgb[j] : 0.f;        // preloaded XG entry for t=0
    unsigned* flagv = flags + b * 32;           // 128B-padded 4-slot group
    __syncthreads();

    for (int t = 0; t < nsteps; ++t) {
        // acc = Whh[j][q*128 : q*128+128] . h[q*128 : q*128+128]
        float acc0 = 0.f, acc1 = 0.f;
        const int hbase = q * 128;
#pragma unroll
        for (int kk = 0; kk < 32; kk += 2) {
            float4 h0 = *(const float4*)&hs[hbase + kk * 4];
            float4 h1 = *(const float4*)&hs[hbase + kk * 4 + 4];
            acc0 += wv[kk].x * h0.x + wv[kk].y * h0.y
                  + wv[kk].z * h0.z + wv[kk].w * h0.w;
            acc1 += wv[kk + 1].x * h1.x + wv[kk + 1].y * h1.y
                  + wv[kk + 1].z * h1.z + wv[kk + 1].w * h1.w;
        }
        float acc = acc0 + acc1;
        acc += __shfl_xor(acc, 1);              // q0+q1 halves
        if (q == 0) gbuf[r] = acc + xgv;
        // prefetch next step's XG entry while the group synchronizes
        if (q == 0 && t + 1 < nsteps) xgv = xgb[(size_t)(t + 1) * 1024 + j];
        __syncthreads();                        // (1) gbuf ready; hs reads done

        if (tid < 64) {                         // wave 0: cell + publish
            float ig = gbuf[tid], fg = gbuf[64 + tid];
            float gg = gbuf[128 + tid], og = gbuf[192 + tid];
            float cn = sigm(fg) * creg + sigm(ig) * tanhf(gg);
            float hn = sigm(og) * tanhf(cn);
            creg = cn; hreg = hn;
            __hip_atomic_store(&hx[((size_t)(t & 1) * 64 + b) * 256 + p * 64 + tid],
                               hn, __ATOMIC_RELAXED, __HIP_MEMORY_SCOPE_AGENT);
            if (h_seq) h_seq[((size_t)b * TSEQ + t) * 256 + p * 64 + tid] = hn;
            // data stores acknowledged at the coherence point, THEN the flag:
            asm volatile("s_waitcnt vmcnt(0)" ::: "memory");
            if (tid == 0)
                __hip_atomic_store(&flagv[p], (unsigned)(t + 1),
                                   __ATOMIC_RELAXED, __HIP_MEMORY_SCOPE_AGENT);
        }
        if (tid < 256) {                        // waves 0-3: poll then gather
            if ((tid & 63) < 4) {
                while (__hip_atomic_load(&flagv[tid & 63], __ATOMIC_RELAXED,
                                         __HIP_MEMORY_SCOPE_AGENT)
                       < (unsigned)(t + 1)) {}
            }
            // wave reconverges only when all 4 slots confirmed
            asm volatile("" ::: "memory");
            hs[tid] = __hip_atomic_load(&hx[((size_t)(t & 1) * 64 + b) * 256 + tid],
                                        __ATOMIC_RELAXED, __HIP_MEMORY_SCOPE_AGENT);
        }
        __syncthreads();                        // (2) hs holds h_{t+1}
    }

    if (h_fin && tid < 64) {
        h_fin[b * 256 + p * 64 + tid] = hreg;
        c_fin[b * 256 + p * 64 + tid] = creg;
    }
}

// Decode cell: sum 4 split-K gate partials + precomputed ctx-gates row, LSTM cell.
__global__ void dec_cell(const float* __restrict__ gpart, const float* __restrict__ allg,
                         float* __restrict__ h, float* __restrict__ c)
{
    const int b = blockIdx.x, d = threadIdx.x;
    const size_t zs = (size_t)64 * 1024;
    float g4[4];
#pragma unroll
    for (int gg = 0; gg < 4; ++gg) {
        int j = gg * 256 + d;
        float s = allg[(size_t)b * TSEQ * 1024 + j];
        s += gpart[(size_t)b * 1024 + j];
        s += gpart[zs + (size_t)b * 1024 + j];
        s += gpart[2 * zs + (size_t)b * 1024 + j];
        s += gpart[3 * zs + (size_t)b * 1024 + j];
        g4[gg] = s;
    }
    float cn = sigm(g4[1]) * c[b * 256 + d] + sigm(g4[0]) * tanhf(g4[2]);
    float hn = sigm(g4[3]) * tanhf(cn);
    c[b * 256 + d] = cn;
    h[b * 256 + d] = hn;
}

// Logits tile: all 64 batch rows x 64 vocab cols, K=256. Writes cap_prob and
// per-(batch, vocab-slice) argmax partials. First-max tie rule preserved by
// ascending-index scans with strict >.
__global__ __launch_bounds__(256)
void dec_logits(const float* __restrict__ h, const float* __restrict__ w2,
                const float* __restrict__ b2, float* __restrict__ outp,
                float* __restrict__ pmax)
{
    const int nt = blockIdx.x;   // 500 slices of 64 vocab cols
    const int tid = threadIdx.x, tx = tid & 15, ty = tid >> 4;
    __shared__ float As[16][68];
    __shared__ float Bs[16][68];
    __shared__ float pmv[64][17];
    __shared__ float pmi[64][17];

    const float* W = w2 + (size_t)nt * 64 * 256;
    const int lr = tid >> 2, lk = (tid & 3) * 4;
    float acc[4][4] = {};

    for (int k0 = 0; k0 < 256; k0 += 16) {
        float4 a4 = *(const float4*)(h + (size_t)lr * 256 + k0 + lk);
        float4 b4 = *(const float4*)(W + (size_t)lr * 256 + k0 + lk);
        As[lk + 0][lr] = a4.x; As[lk + 1][lr] = a4.y;
        As[lk + 2][lr] = a4.z; As[lk + 3][lr] = a4.w;
        Bs[lk + 0][lr] = b4.x; Bs[lk + 1][lr] = b4.y;
        Bs[lk + 2][lr] = b4.z; Bs[lk + 3][lr] = b4.w;
        __syncthreads();
#pragma unroll
        for (int k = 0; k < 16; ++k) {
            float4 av = *(const float4*)&As[k][ty * 4];
            float4 bv = *(const float4*)&Bs[k][tx * 4];
            acc[0][0] += av.x * bv.x; acc[0][1] += av.x * bv.y;
            acc[0][2] += av.x * bv.z; acc[0][3] += av.x * bv.w;
            acc[1][0] += av.y * bv.x; acc[1][1] += av.y * bv.y;
            acc[1][2] += av.y * bv.z; acc[1][3] += av.y * bv.w;
            acc[2][0] += av.z * bv.x; acc[2][1] += av.z * bv.y;
            acc[2][2] += av.z * bv.z; acc[2][3] += av.z * bv.w;
            acc[3][0] += av.w * bv.x; acc[3][1] += av.w * bv.y;
            acc[3][2] += av.w * bv.z; acc[3][3] += av.w * bv.w;
        }
        __syncthreads();
    }

    const int colbase = nt * 64 + tx * 4;
    float bb[4];
#pragma unroll
    for (int j = 0; j < 4; ++j) bb[j] = b2[colbase + j];

#pragma unroll
    for (int i = 0; i < 4; ++i) {
        int b = ty * 4 + i;
        float4 v;
        v.x = acc[i][0] + bb[0]; v.y = acc[i][1] + bb[1];
        v.z = acc[i][2] + bb[2]; v.w = acc[i][3] + bb[3];
        *(float4*)(outp + (size_t)b * ((size_t)DEC_T * VOCAB) + colbase) = v;
        float bestv = v.x; int bestj = colbase;
        if (v.y > bestv) { bestv = v.y; bestj = colbase + 1; }
        if (v.z > bestv) { bestv = v.z; bestj = colbase + 2; }
        if (v.w > bestv) { bestv = v.w; bestj = colbase + 3; }
        pmv[b][tx] = bestv;
        pmi[b][tx] = (float)bestj;
    }
    __syncthreads();
    if (tid < 64) {
        float bv = pmv[tid][0], bj = pmi[tid][0];
#pragma unroll
        for (int s = 1; s < 16; ++s) {
            if (pmv[tid][s] > bv) { bv = pmv[tid][s]; bj = pmi[tid][s]; }
        }
        pmax[((size_t)tid * 500 + nt) * 2 + 0] = bv;
        pmax[((size_t)tid * 500 + nt) * 2 + 1] = bj;
    }
}

// Reduce 500 argmax partials per batch row -> token; emit caption (as float)
// and next-step concat input y = [emb[tok], h].
__global__ void dec_finish(const float* __restrict__ pmax, const float* __restrict__ emb,
                           const float* __restrict__ h, float* __restrict__ y,
                           float* __restrict__ cap_out)
{
    const int b = blockIdx.x, tid = threadIdx.x;
    __shared__ float bv[256];
    __shared__ int   bi[256];
    float best = -INFINITY; int bidx = 0x7fffffff;
    for (int s = tid; s < 500; s += 256) {
        float v = pmax[((size_t)b * 500 + s) * 2 + 0];
        int   ix = (int)pmax[((size_t)b * 500 + s) * 2 + 1];
        if (v > best || (v == best && ix < bidx)) { best = v; bidx = ix; }
    }
    bv[tid] = best; bi[tid] = bidx;
    __syncthreads();
    for (int s = 128; s > 0; s >>= 1) {
        if (tid < s) {
            if (bv[tid + s] > bv[tid] ||
                (bv[tid + s] == bv[tid] && bi[tid + s] < bi[tid])) {
                bv[tid] = bv[tid + s]; bi[tid] = bi[tid + s];
            }
        }
        __syncthreads();
    }
    int tok = bi[0];
    if (tid == 0) cap_out[(size_t)b * DEC_T] = (float)tok;
    y[(size_t)b * 512 + tid]       = emb[(size_t)tok * 256 + tid];
    y[(size_t)b * 512 + 256 + tid] = h[(size_t)b * 256 + tid];
}

// y for t=0: tok = BOS = 0.
__global__ void y_init(const float* __restrict__ emb, const float* __restrict__ h,
                       float* __restrict__ y)
{
    const int b = blockIdx.x, tid = threadIdx.x;
    y[(size_t)b * 512 + tid]       = emb[tid];
    y[(size_t)b * 512 + 256 + tid] = h[(size_t)b * 256 + tid];
}

// ---------------------------------------------------------------------------
extern "C" void kernel_launch(void* const* d_in, const int* in_sizes, int n_in,
                              void* d_out, int out_size, void* d_ws, size_t ws_size,
                              hipStream_t stream)
{
    const float* video  = (const float*)d_in[0];
    const float* w1     = (const float*)d_in[1];
    const float* b1     = (const float*)d_in[2];
    const float* w2     = (const float*)d_in[3];
    const float* b2     = (const float*)d_in[4];
    const float* l1_wih = (const float*)d_in[5];
    const float* l1_whh = (const float*)d_in[6];
    const float* l1_bih = (const float*)d_in[7];
    const float* l1_bhh = (const float*)d_in[8];
    const float* l2_wih = (const float*)d_in[9];
    const float* l2_whh = (const float*)d_in[10];
    const float* l2_bih = (const float*)d_in[11];
    const float* l2_bhh = (const float*)d_in[12];
    const float* emb    = (const float*)d_in[13];

    float* out_f = (float*)d_out;           // [64*49] caption (as float) | [64*49*32000] cap_prob
    float* ws    = (float*)d_ws;

    // workspace layout (floats)
    float* v      = ws;                            // 5120*256      = 1,310,720
    float* vid    = v      + 1310720;              // 64*129*256    = 2,113,536
    float* hx     = vid    + 2113536;              // 2*64*256 = 32,768 (region 262,144)
    unsigned* flags = (unsigned*)(hx + 262144);    // 4096 uints (2 layers x 64 groups x 32)
    float* wcat   = hx     + 524288;               // 1024*512      = 524,288
    float* hbuf   = wcat   + 524288;               // 16,384
    float* cbuf   = hbuf   + 16384;                // 16,384
    float* ybuf   = cbuf   + 16384;                // 64*512        = 32,768
    float* gpart  = ybuf   + 32768;                // 4*64*1024     = 262,144
    float* pmax   = gpart  + 262144;               // 64*500*2      = 64,000
    float* xg     = pmax   + 64000;                // 64*129*1024   = 8,454,144  (also holds gemm1 partials)
    float* vpart  = xg;                            // 4*5120*256 = 5,242,880 <= XG region

    // prep: flags + concat weights
    zero_flags<<<16, 256, 0, stream>>>(flags);
    pack_wcat<<<512, 256, 0, stream>>>(l2_wih, l2_whh, wcat);

    // GEMM1: v = video @ w1.T + b1   (split-K=4 for load balance, then reduce)
    gemm_nt<<<dim3(80, 4, 4), 256, 0, stream>>>(video, FRAME, w1, FRAME,
                                                vpart, (long long)5120 * 256, 256,
                                                1024, nullptr, nullptr, 1, 1);
    reduce_v<<<1280, 256, 0, stream>>>(vpart, b1, v);

    // XG = v @ l1_wih.T + (bih + bhh), rows remapped b*129+t; bias-only rows t>=80
    gemm_nt<<<dim3(80, 16, 1), 256, 0, stream>>>(v, HID, l1_wih, HID,
                                                 xg, 0, 1024, HID,
                                                 l1_bih, l1_bhh, VSTEP, TSEQ);
    fill_bias<<<64 * DEC_T, 256, 0, stream>>>(xg, l1_bih, l1_bhh);

    // LSTM1: 129 steps, emits vid_out (4 blocks per batch, weights in VGPRs)
    lstm_sync<<<256, 512, 0, stream>>>(l1_whh, xg, TSEQ, vid, nullptr, nullptr,
                                       hx, flags);

    // XG = vid_out @ l2_wih[:,256:].T + (bih + bhh)   (x first half is zeros for enc)
    gemm_nt<<<dim3(129, 16, 1), 256, 0, stream>>>(vid, HID, l2_wih + 256, 512,
                                                  xg, 0, 1024, HID,
                                                  l2_bih, l2_bhh, 1, 1);

    // LSTM2 encode: 80 steps -> (h2, c2)
    lstm_sync<<<256, 512, 0, stream>>>(l2_whh, xg, VSTEP, nullptr, hbuf, cbuf,
                                       hx, flags + 2048);

    // decode
    y_init<<<64, 256, 0, stream>>>(emb, hbuf, ybuf);
    for (int t = 0; t < DEC_T; ++t) {
        // gates partials = y @ Wcat.T  (K=512 split 4 ways)
        gemm_nt<<<dim3(1, 16, 4), 256, 0, stream>>>(ybuf, 512, wcat, 512,
                                                    gpart, (long long)64 * 1024, 1024,
                                                    128, nullptr, nullptr, 1, 1);
        dec_cell<<<64, 256, 0, stream>>>(gpart, xg + (size_t)(VSTEP + t) * 1024, hbuf, cbuf);
        dec_logits<<<500, 256, 0, stream>>>(hbuf, w2, b2,
                                            out_f + 3136 + (size_t)t * VOCAB, pmax);
        dec_finish<<<64, 256, 0, stream>>>(pmax, emb, hbuf, ybuf, out_f + t);
    }
}